// Round 4
// baseline (9359.067 us; speedup 1.0000x reference)
//
#include <hip/hip_runtime.h>
#include <hip/hip_fp16.h>
#include <cstdint>
#include <cstddef>

#define TT 2048
#define VV 32000
#define EE 512
#define HH 1024

typedef __bf16 bf16x8 __attribute__((ext_vector_type(8)));
typedef float f32x4 __attribute__((ext_vector_type(4)));
typedef unsigned uint32x4 __attribute__((ext_vector_type(4)));

static __device__ __forceinline__ unsigned short f2b(float f) {
    unsigned u = __float_as_uint(f);
    unsigned r = (u + 0x7fffu + ((u >> 16) & 1u)) >> 16;   // RNE
    return (unsigned short)r;
}
static __device__ __forceinline__ float hf(unsigned bits) {   // f16 bits -> f32
    return __half2float(__ushort_as_half((unsigned short)(bits & 0xffffu)));
}
static __device__ __forceinline__ unsigned fh(float f) {      // f32 -> f16 bits
    return (unsigned)__half_as_ushort(__float2half(f));
}
static __device__ __forceinline__ float sigm(float x) {
    return __builtin_amdgcn_rcpf(1.f + __expf(-x));
}
static __device__ __forceinline__ float tanh_s(float x) {     // NaN-safe tanh
    float a = fabsf(x);
    float e = __expf(-2.f * a);
    float r = (1.f - e) * __builtin_amdgcn_rcpf(1.f + e);
    return copysignf(r, x);
}

// 2x16B bypassing poll load (sc0 sc1: skip L1/L2, read coherence point)
static __device__ __forceinline__ void poll2(const unsigned short* p0,
                                             const unsigned short* p1,
                                             uint32x4& a, uint32x4& b) {
    asm volatile(
        "global_load_dwordx4 %0, %2, off sc0 sc1\n\t"
        "global_load_dwordx4 %1, %3, off sc0 sc1\n\t"
        "s_waitcnt vmcnt(0)"
        : "=&v"(a), "=&v"(b)
        : "v"(p0), "v"(p1)
        : "memory");
}
static __device__ __forceinline__ bool ok4(uint32x4 v) {
    bool bad = false;
#pragma unroll
    for (int i = 0; i < 4; ++i) {
        unsigned w = v[i];
        bad |= ((w & 0xffffu) == 0xffffu) | ((w >> 16) == 0xffffu);
    }
    return !bad;
}
static __device__ __forceinline__ void flag_set(int* f, int v) {
    __hip_atomic_store(f, v, __ATOMIC_RELEASE, __HIP_MEMORY_SCOPE_WORKGROUP);
}
static __device__ __forceinline__ void flag_spin(int* f, int want) {
    while (__hip_atomic_load(f, __ATOMIC_ACQUIRE, __HIP_MEMORY_SCOPE_WORKGROUP) < want) {}
}

// ---------------- embedding gather -> bf16 ----------------
__global__ __launch_bounds__(128) void embed_kernel(
    const int* __restrict__ tok, const float* __restrict__ emb,
    unsigned short* __restrict__ xs_b) {
    int t = blockIdx.x;
    int e4 = threadIdx.x;
    const float4* src = (const float4*)(emb + (size_t)tok[t] * EE);
    float4 v = src[e4];
    ushort4 o;
    o.x = f2b(v.x); o.y = f2b(v.y); o.z = f2b(v.z); o.w = f2b(v.w);
    ((ushort4*)(xs_b + (size_t)t * EE))[e4] = o;
}

// ---------------- generic f32 -> bf16 ----------------
__global__ __launch_bounds__(256) void f32_to_bf16(
    const float* __restrict__ in, unsigned short* __restrict__ out, long n4) {
    long i = (long)blockIdx.x * blockDim.x + threadIdx.x;
    long stride = (long)gridDim.x * blockDim.x;
    for (; i < n4; i += stride) {
        float4 v = ((const float4*)in)[i];
        ushort4 o;
        o.x = f2b(v.x); o.y = f2b(v.y); o.z = f2b(v.z); o.w = f2b(v.w);
        ((ushort4*)out)[i] = o;
    }
}

// ---------------- bf16 MFMA GEMM: C[M,N] = A[M,K] * B[N,K]^T + bias ----------------
__global__ __launch_bounds__(256) void gemm_bf16_nt(
    const unsigned short* __restrict__ A,   // [M][K] bf16 bits
    const unsigned short* __restrict__ B,   // [N][K] bf16 bits
    const float* __restrict__ bias1,        // [N] or null
    const float* __restrict__ bias2,        // [N] or null
    float* __restrict__ C,                  // [M][N]
    int K, int N) {
    __shared__ unsigned short ldsA[128 * 64];
    __shared__ unsigned short ldsB[128 * 64];
    const int tid = threadIdx.x;
    const int l = tid & 63;
    const int w = tid >> 6;
    const int wm = (w >> 1) * 64;
    const int wn = (w & 1) * 64;
    const int bm = blockIdx.y, bn = blockIdx.x;
    const size_t a_base = (size_t)bm * 128 * K;
    const size_t b_base = (size_t)bn * 128 * K;
    const int srow = tid >> 3;
    const int skc = tid & 7;

    f32x4 acc[4][4];
    for (int i = 0; i < 4; ++i)
        for (int j = 0; j < 4; ++j)
            acc[i][j] = (f32x4){0.f, 0.f, 0.f, 0.f};

    for (int kt = 0; kt < K; kt += 64) {
        uint4 av[4], bv[4];
#pragma unroll
        for (int i = 0; i < 4; ++i) {
            int row = srow + i * 32;
            av[i] = ((const uint4*)(A + a_base + (size_t)row * K + kt))[skc];
            bv[i] = ((const uint4*)(B + b_base + (size_t)row * K + kt))[skc];
        }
        __syncthreads();
#pragma unroll
        for (int i = 0; i < 4; ++i) {
            int row = srow + i * 32;
            int off = row * 128 + ((skc * 16) ^ ((row & 7) << 4));
            *(uint4*)((char*)ldsA + off) = av[i];
            *(uint4*)((char*)ldsB + off) = bv[i];
        }
        __syncthreads();
#pragma unroll
        for (int ks = 0; ks < 2; ++ks) {
            bf16x8 af[4], bfr[4];
            int kb = ks * 64 + (l >> 4) * 16;
#pragma unroll
            for (int f = 0; f < 4; ++f) {
                int ar = wm + f * 16 + (l & 15);
                af[f] = *(const bf16x8*)((const char*)ldsA + ar * 128 + (kb ^ ((ar & 7) << 4)));
                int br = wn + f * 16 + (l & 15);
                bfr[f] = *(const bf16x8*)((const char*)ldsB + br * 128 + (kb ^ ((br & 7) << 4)));
            }
#pragma unroll
            for (int fm = 0; fm < 4; ++fm)
#pragma unroll
                for (int fn = 0; fn < 4; ++fn)
                    acc[fm][fn] = __builtin_amdgcn_mfma_f32_16x16x32_bf16(
                        af[fm], bfr[fn], acc[fm][fn], 0, 0, 0);
        }
    }
    const int r0 = (l >> 4) * 4, cn = (l & 15);
#pragma unroll
    for (int fm = 0; fm < 4; ++fm)
#pragma unroll
        for (int fn = 0; fn < 4; ++fn) {
            int col = bn * 128 + wn + fn * 16 + cn;
            float bb = (bias1 ? bias1[col] : 0.f) + (bias2 ? bias2[col] : 0.f);
#pragma unroll
            for (int r = 0; r < 4; ++r) {
                int rowg = bm * 128 + wm + fm * 16 + r0 + r;
                C[(size_t)rowg * N + col] = acc[fm][fn][r] + bb;
            }
        }
}

// ---------------- fused 2-layer pipelined LSTM recurrence ----------------
// 192 blocks x 512 threads. Blocks 0..63: layer 0 (8 waves x 2 units).
// Blocks 64..191: layer 1 (8 waves x 1 unit), pipelined 1 step behind.
// Comm: raw f16 h, full history per layer; 0xFFFF (f16 NaN) = "not ready"
// sentinel (h = o*tanh(c) can never be NaN). One wave per block polls
// (2x16B bypassing loads/lane) and broadcasts via LDS + flag; weights are
// fp32 pinned in VGPRs via asm.
__global__ __launch_bounds__(512, 2) void lstm_fused(
    const float* __restrict__ Whh0,           // [4H][H]
    const float* __restrict__ pre0,           // [T][4H] (x-proj + biases, layer 0)
    const float* __restrict__ Wih1,           // [4H][H]
    const float* __restrict__ Whh1,           // [4H][H]
    const float* __restrict__ bih1,           // [4H]
    const float* __restrict__ bhh1,           // [4H]
    unsigned short* __restrict__ hist0,       // [T][H] f16 h0 history (0xFF init)
    unsigned short* __restrict__ hist1,       // [T][H] f16 h1 history (0xFF init)
    unsigned short* __restrict__ y1b,         // [T][H] bf16 layer-1 output
    float* __restrict__ hfb,                  // out + T*V      (h stack [2][H])
    float* __restrict__ cfb) {                // out + T*V + 2H (c stack [2][H])
    const int tid  = threadIdx.x;
    const int wv   = tid >> 6;
    const int lane = tid & 63;

    __shared__ float hA[2][HH];
    __shared__ float hB[2][HH];
    __shared__ int flagA, flagB;
    __shared__ int wprog[8];
    if (tid == 0) { flagA = 0; flagB = 0; }
    if (tid < 8) wprog[tid] = 0;
    __syncthreads();

    if (blockIdx.x < 64) {
        // ================= layer 0: 2 units per wave =================
        const int wid = blockIdx.x * 8 + wv;      // 0..511
        const int j0 = 2 * wid, j1 = j0 + 1;
        float w0[4][16], w1[4][16];
#pragma unroll
        for (int g = 0; g < 4; ++g)
#pragma unroll
            for (int k = 0; k < 16; ++k) {
                w0[g][k] = Whh0[(size_t)(g * HH + j0) * HH + lane + 64 * k];
                w1[g][k] = Whh0[(size_t)(g * HH + j1) * HH + lane + 64 * k];
            }
#pragma unroll
        for (int g = 0; g < 4; ++g)
#pragma unroll
            for (int k = 0; k < 16; ++k)
                asm volatile("" : "+v"(w0[g][k]), "+v"(w1[g][k]));

        float c0 = 0.f, c1 = 0.f;
        float px[8];
#pragma unroll
        for (int g = 0; g < 4; ++g) {
            px[g]     = pre0[(size_t)g * HH + j0];
            px[4 + g] = pre0[(size_t)g * HH + j1];
        }

        for (int t = 0; t < TT; ++t) {
            const int par = t & 1;
            // issue next-step px loads (overlap with poll RT)
            float nx[8];
#pragma unroll
            for (int g = 0; g < 8; ++g) nx[g] = 0.f;
            if (t + 1 < TT) {
                const float* p = pre0 + (size_t)(t + 1) * 4 * HH;
#pragma unroll
                for (int g = 0; g < 4; ++g) {
                    nx[g]     = p[(size_t)g * HH + j0];
                    nx[4 + g] = p[(size_t)g * HH + j1];
                }
            }
            if (wv == 0) {
                if (t > 0) {
                    const unsigned short* base = hist0 + (size_t)(t - 1) * HH;
                    uint32x4 va, vb;
                    do {
                        poll2(base + 8 * lane, base + 8 * (lane + 64), va, vb);
                    } while (!(ok4(va) & ok4(vb)));
                    float4 f0, f1, f2, f3;
                    f0.x = hf(va[0]); f0.y = hf(va[0] >> 16); f0.z = hf(va[1]); f0.w = hf(va[1] >> 16);
                    f1.x = hf(va[2]); f1.y = hf(va[2] >> 16); f1.z = hf(va[3]); f1.w = hf(va[3] >> 16);
                    f2.x = hf(vb[0]); f2.y = hf(vb[0] >> 16); f2.z = hf(vb[1]); f2.w = hf(vb[1] >> 16);
                    f3.x = hf(vb[2]); f3.y = hf(vb[2] >> 16); f3.z = hf(vb[3]); f3.w = hf(vb[3] >> 16);
                    *(float4*)&hA[par][8 * lane]       = f0;
                    *(float4*)&hA[par][8 * lane + 4]   = f1;
                    *(float4*)&hA[par][512 + 8 * lane]     = f2;
                    *(float4*)&hA[par][512 + 8 * lane + 4] = f3;
                } else {
                    float4 z = {0.f, 0.f, 0.f, 0.f};
                    *(float4*)&hA[par][8 * lane]       = z;
                    *(float4*)&hA[par][8 * lane + 4]   = z;
                    *(float4*)&hA[par][512 + 8 * lane]     = z;
                    *(float4*)&hA[par][512 + 8 * lane + 4] = z;
                }
                flag_set(&flagA, t + 1);
            } else {
                flag_spin(&flagA, t + 1);
            }
            // dot
            float d00 = 0.f, d01 = 0.f, d02 = 0.f, d03 = 0.f;
            float d10 = 0.f, d11 = 0.f, d12 = 0.f, d13 = 0.f;
#pragma unroll
            for (int m = 0; m < 16; ++m) {
                float hv = hA[par][lane + 64 * m];
                d00 += w0[0][m] * hv; d01 += w0[1][m] * hv;
                d02 += w0[2][m] * hv; d03 += w0[3][m] * hv;
                d10 += w1[0][m] * hv; d11 += w1[1][m] * hv;
                d12 += w1[2][m] * hv; d13 += w1[3][m] * hv;
            }
#pragma unroll
            for (int off = 32; off; off >>= 1) {
                d00 += __shfl_xor(d00, off); d01 += __shfl_xor(d01, off);
                d02 += __shfl_xor(d02, off); d03 += __shfl_xor(d03, off);
                d10 += __shfl_xor(d10, off); d11 += __shfl_xor(d11, off);
                d12 += __shfl_xor(d12, off); d13 += __shfl_xor(d13, off);
            }
            float i0 = sigm(px[0] + d00), f0g = sigm(px[1] + d01);
            float g0 = tanh_s(px[2] + d02), o0 = sigm(px[3] + d03);
            c0 = f0g * c0 + i0 * g0;
            float h0n = o0 * tanh_s(c0);
            float i1 = sigm(px[4] + d10), f1g = sigm(px[5] + d11);
            float g1 = tanh_s(px[6] + d12), o1 = sigm(px[7] + d13);
            c1 = f1g * c1 + i1 * g1;
            float h1n = o1 * tanh_s(c1);
            if (lane == 0) {
                unsigned pack = fh(h0n) | (fh(h1n) << 16);
                asm volatile("global_store_dword %0, %1, off sc0 sc1"
                             :: "v"(hist0 + (size_t)t * HH + j0), "v"(pack) : "memory");
                if (t == TT - 1) {
                    hfb[j0] = h0n; hfb[j1] = h1n;
                    cfb[j0] = c0;  cfb[j1] = c1;
                }
            }
#pragma unroll
            for (int g = 0; g < 8; ++g) px[g] = nx[g];
        }
    } else {
        // ================= layer 1: 1 unit per wave =================
        const int wid = (blockIdx.x - 64) * 8 + wv;   // 0..1023
        const int j = wid;
        float wi[4][16], wh[4][16], bs[4];
#pragma unroll
        for (int g = 0; g < 4; ++g) {
#pragma unroll
            for (int k = 0; k < 16; ++k) {
                wi[g][k] = Wih1[(size_t)(g * HH + j) * HH + lane + 64 * k];
                wh[g][k] = Whh1[(size_t)(g * HH + j) * HH + lane + 64 * k];
            }
            bs[g] = bih1[g * HH + j] + bhh1[g * HH + j];
        }
#pragma unroll
        for (int g = 0; g < 4; ++g)
#pragma unroll
            for (int k = 0; k < 16; ++k)
                asm volatile("" : "+v"(wi[g][k]), "+v"(wh[g][k]));

        float c = 0.f;
        for (int t = 0; t < TT; ++t) {
            const int par = t & 1;
            if (wv == 0) {
                // back-pressure: don't overwrite hA[par] until all waves done t-2
                if (t >= 2) {
#pragma unroll
                    for (int q = 0; q < 8; ++q) flag_spin(&wprog[q], t - 1);
                }
                const unsigned short* base = hist0 + (size_t)t * HH;
                uint32x4 va, vb;
                do {
                    poll2(base + 8 * lane, base + 8 * (lane + 64), va, vb);
                } while (!(ok4(va) & ok4(vb)));
                float4 f0, f1, f2, f3;
                f0.x = hf(va[0]); f0.y = hf(va[0] >> 16); f0.z = hf(va[1]); f0.w = hf(va[1] >> 16);
                f1.x = hf(va[2]); f1.y = hf(va[2] >> 16); f1.z = hf(va[3]); f1.w = hf(va[3] >> 16);
                f2.x = hf(vb[0]); f2.y = hf(vb[0] >> 16); f2.z = hf(vb[1]); f2.w = hf(vb[1] >> 16);
                f3.x = hf(vb[2]); f3.y = hf(vb[2] >> 16); f3.z = hf(vb[3]); f3.w = hf(vb[3] >> 16);
                *(float4*)&hA[par][8 * lane]       = f0;
                *(float4*)&hA[par][8 * lane + 4]   = f1;
                *(float4*)&hA[par][512 + 8 * lane]     = f2;
                *(float4*)&hA[par][512 + 8 * lane + 4] = f3;
                flag_set(&flagA, t + 1);
                flag_spin(&flagB, t + 1);
            } else if (wv == 1) {
                if (t >= 2) {
#pragma unroll
                    for (int q = 0; q < 8; ++q) flag_spin(&wprog[q], t - 1);
                }
                if (t > 0) {
                    const unsigned short* base = hist1 + (size_t)(t - 1) * HH;
                    uint32x4 va, vb;
                    do {
                        poll2(base + 8 * lane, base + 8 * (lane + 64), va, vb);
                    } while (!(ok4(va) & ok4(vb)));
                    float4 f0, f1, f2, f3;
                    f0.x = hf(va[0]); f0.y = hf(va[0] >> 16); f0.z = hf(va[1]); f0.w = hf(va[1] >> 16);
                    f1.x = hf(va[2]); f1.y = hf(va[2] >> 16); f1.z = hf(va[3]); f1.w = hf(va[3] >> 16);
                    f2.x = hf(vb[0]); f2.y = hf(vb[0] >> 16); f2.z = hf(vb[1]); f2.w = hf(vb[1] >> 16);
                    f3.x = hf(vb[2]); f3.y = hf(vb[2] >> 16); f3.z = hf(vb[3]); f3.w = hf(vb[3] >> 16);
                    *(float4*)&hB[par][8 * lane]       = f0;
                    *(float4*)&hB[par][8 * lane + 4]   = f1;
                    *(float4*)&hB[par][512 + 8 * lane]     = f2;
                    *(float4*)&hB[par][512 + 8 * lane + 4] = f3;
                } else {
                    float4 z = {0.f, 0.f, 0.f, 0.f};
                    *(float4*)&hB[par][8 * lane]       = z;
                    *(float4*)&hB[par][8 * lane + 4]   = z;
                    *(float4*)&hB[par][512 + 8 * lane]     = z;
                    *(float4*)&hB[par][512 + 8 * lane + 4] = z;
                }
                flag_set(&flagB, t + 1);
                flag_spin(&flagA, t + 1);
            } else {
                flag_spin(&flagA, t + 1);
                flag_spin(&flagB, t + 1);
            }
            float d0 = bs[0], d1 = bs[1], d2 = bs[2], d3 = bs[3];
#pragma unroll
            for (int m = 0; m < 16; ++m) {
                float ha = hA[par][lane + 64 * m];
                float hb = hB[par][lane + 64 * m];
                d0 += wi[0][m] * ha + wh[0][m] * hb;
                d1 += wi[1][m] * ha + wh[1][m] * hb;
                d2 += wi[2][m] * ha + wh[2][m] * hb;
                d3 += wi[3][m] * ha + wh[3][m] * hb;
            }
            // subtract (64-1)*bias added via init trick? No: bias added once below.
            d0 -= bs[0]; d1 -= bs[1]; d2 -= bs[2]; d3 -= bs[3];
#pragma unroll
            for (int off = 32; off; off >>= 1) {
                d0 += __shfl_xor(d0, off); d1 += __shfl_xor(d1, off);
                d2 += __shfl_xor(d2, off); d3 += __shfl_xor(d3, off);
            }
            float i_ = sigm(bs[0] + d0), f_ = sigm(bs[1] + d1);
            float g_ = tanh_s(bs[2] + d2), o_ = sigm(bs[3] + d3);
            c = f_ * c + i_ * g_;
            float h = o_ * tanh_s(c);
            if (lane == 0) {
                asm volatile("global_store_short %0, %1, off sc0 sc1"
                             :: "v"(hist1 + (size_t)t * HH + j), "v"(fh(h)) : "memory");
                y1b[(size_t)t * HH + j] = f2b(h);
                if (t == TT - 1) { hfb[HH + j] = h; cfb[HH + j] = c; }
            }
            flag_set(&wprog[wv], t + 1);
        }
    }
}

// ---------------- row softmax over V=32000, in place ----------------
__global__ __launch_bounds__(256) void softmax_kernel(float* __restrict__ data) {
    const int row = blockIdx.x;
    const int tid = threadIdx.x;
    float* p = data + (size_t)row * VV;
    float m = -1e30f, s = 0.f;
    for (int i = tid * 4; i < VV; i += 1024) {
        float4 v = *(const float4*)(p + i);
        float x[4] = {v.x, v.y, v.z, v.w};
#pragma unroll
        for (int q = 0; q < 4; ++q) {
            float xv = x[q];
            if (xv > m) { s = s * __expf(m - xv) + 1.f; m = xv; }
            else s += __expf(xv - m);
        }
    }
#pragma unroll
    for (int off = 32; off; off >>= 1) {
        float mo = __shfl_xor(m, off);
        float so = __shfl_xor(s, off);
        float mn = fmaxf(m, mo);
        s = s * __expf(m - mn) + so * __expf(mo - mn);
        m = mn;
    }
    __shared__ float sm[4], ss[4];
    int wvv = tid >> 6;
    if ((tid & 63) == 0) { sm[wvv] = m; ss[wvv] = s; }
    __syncthreads();
    float M = fmaxf(fmaxf(sm[0], sm[1]), fmaxf(sm[2], sm[3]));
    float S = ss[0] * __expf(sm[0] - M) + ss[1] * __expf(sm[1] - M) +
              ss[2] * __expf(sm[2] - M) + ss[3] * __expf(sm[3] - M);
    float inv = 1.f / S;
    for (int i = tid * 4; i < VV; i += 1024) {
        float4 v = *(const float4*)(p + i);
        v.x = __expf(v.x - M) * inv;
        v.y = __expf(v.y - M) * inv;
        v.z = __expf(v.z - M) * inv;
        v.w = __expf(v.w - M) * inv;
        *(float4*)(p + i) = v;
    }
}

extern "C" void kernel_launch(void* const* d_in, const int* in_sizes, int n_in,
                              void* d_out, int out_size, void* d_ws, size_t ws_size,
                              hipStream_t stream) {
    const int*   inputs = (const int*)d_in[0];
    const float* emb    = (const float*)d_in[1];
    const float* w_ih0  = (const float*)d_in[2];
    const float* w_hh0  = (const float*)d_in[3];
    const float* b_ih0  = (const float*)d_in[4];
    const float* b_hh0  = (const float*)d_in[5];
    const float* w_ih1  = (const float*)d_in[6];
    const float* w_hh1  = (const float*)d_in[7];
    const float* b_ih1  = (const float*)d_in[8];
    const float* b_hh1  = (const float*)d_in[9];
    const float* w_out  = (const float*)d_in[10];
    const float* b_out  = (const float*)d_in[11];
    float* out = (float*)d_out;

    char* ws = (char*)d_ws;
    size_t off = 0;
    auto alloc = [&](size_t bytes) -> void* {
        void* p = ws + off;
        off += (bytes + 255) & ~(size_t)255;
        return p;
    };
    float* pre0          = (float*)alloc((size_t)TT * 4 * HH * 4);
    unsigned short* xsb  = (unsigned short*)alloc((size_t)TT * EE * 2);
    unsigned short* w0b  = (unsigned short*)alloc((size_t)4 * HH * EE * 2);
    unsigned short* wob  = (unsigned short*)alloc((size_t)VV * HH * 2);
    unsigned short* y1b  = (unsigned short*)alloc((size_t)TT * HH * 2);
    unsigned short* hist0 = (unsigned short*)alloc((size_t)TT * HH * 2);
    unsigned short* hist1 = (unsigned short*)alloc((size_t)TT * HH * 2);
    if (off > ws_size) return;

    (void)hipMemsetAsync(hist0, 0xFF, (size_t)TT * HH * 2, stream);
    (void)hipMemsetAsync(hist1, 0xFF, (size_t)TT * HH * 2, stream);

    embed_kernel<<<TT, 128, 0, stream>>>(inputs, emb, xsb);
    f32_to_bf16<<<1024, 256, 0, stream>>>(w_ih0, w0b, (long)4 * HH * EE / 4);
    f32_to_bf16<<<2048, 256, 0, stream>>>(w_out, wob, (long)VV * HH / 4);

    // pre0 = xs @ w_ih0^T + b_ih0 + b_hh0
    gemm_bf16_nt<<<dim3(4 * HH / 128, TT / 128), 256, 0, stream>>>(
        xsb, w0b, b_ih0, b_hh0, pre0, EE, 4 * HH);

    // fused pipelined 2-layer recurrence
    lstm_fused<<<192, 512, 0, stream>>>(
        w_hh0, pre0, w_ih1, w_hh1, b_ih1, b_hh1,
        hist0, hist1, y1b,
        out + (size_t)TT * VV, out + (size_t)TT * VV + 2 * HH);

    // logits = ys1 @ w_out^T + b_out  (into d_out, softmax in place after)
    gemm_bf16_nt<<<dim3(VV / 128, TT / 128), 256, 0, stream>>>(
        y1b, wob, b_out, nullptr, out, HH, VV);
    softmax_kernel<<<TT, 256, 0, stream>>>(out);
}